// Round 6
// baseline (45.367 us; speedup 1.0000x reference)
//
#include <hip/hip_runtime.h>

// BlankEmbedding: out[b,s,:] = sum_{m=0..8} c[m] * emb_table[x[b,s-m], :]
// c[m] from 256-entry constexpr LUT over the 8 preblank bits (verified R2-R5).
// Structure: XCD-pinned D-chunking (chunk = bid & 7 -> per-XCD 2 MiB table
// slice, L2-resident) + 8 positions per wave with batched row loads/stores
// for memory-level parallelism. Token window: one 16-lane load + one ballot
// per wave; per-position masks via SALU shifts, tokens via constant readlane.

constexpr int S_LEN = 4096;
constexpr int D_DIM = 2048;
constexpr int NXCD  = 8;
constexpr int CW    = D_DIM / NXCD;   // 256 floats = 1 KiB per chunk
constexpr int PW    = 8;              // positions per wave
constexpr int PB    = 4 * PW;         // positions per block (4 waves)

typedef float f32x4 __attribute__((ext_vector_type(4)));

struct CoefTab { unsigned long long v[256]; };

constexpr CoefTab make_tab() {
    CoefTab t{};
    for (int mask = 0; mask < 256; ++mask) {
        int p[9] = {};
        for (int i = 1; i <= 8; ++i) p[i] = (mask >> (i - 1)) & 1;
        int C[9][9] = {};
        for (int j = 0; j < 9; ++j) C[j][0] = 1;
        for (int k = 1; k <= 8; ++k)
            for (int j = 0; j + k <= 8; ++j)
                for (int m = 8; m >= 1; --m)
                    C[j][m] += p[j + k] * C[j + 1][m - 1];
        unsigned long long pack = 0ULL;
        for (int m = 1; m <= 8; ++m)
            pack |= (unsigned long long)(C[0][m] & 0xff) << ((m - 1) * 8);
        t.v[mask] = pack;
    }
    return t;
}

__device__ __constant__ CoefTab cTab = make_tab();

__global__ __launch_bounds__(256)
void blank_emb_kernel(const int* __restrict__ x,
                      const float* __restrict__ table,
                      float* __restrict__ out) {
    const int bid  = blockIdx.x;
    const int c    = bid & (NXCD - 1);      // D-chunk; round-robin -> XCD-pinned
    const int g    = bid >> 3;              // position group of PB positions
    const int wave = (int)threadIdx.x >> 6;
    const int lane = (int)threadIdx.x & 63;
    const int dcol = c * CW + lane * 4;

    const int pos0 = g * PB + wave * PW;    // first flattened b*S+s of this wave
    const int s0   = pos0 & (S_LEN - 1);    // PW | s0, so wave stays in one row
    const int* __restrict__ xb = x + (pos0 - s0);

    // ---- 16-token window: t = s0 - 8 + lane, lanes 0..15 ----
    int tv = 2048;                          // sentinel: non-blank
    if (lane < 16) {
        const int t = s0 - 8 + lane;        // t <= s0 + 7 <= S_LEN-1
        if (t >= 0) tv = xb[t];
    }
    const unsigned W = (unsigned)__ballot(tv < 16) & 0xFFFFu;  // blank bits

    // ---- phase 1: batched row0 loads (8 independent loads in flight) ----
    f32x4 a[PW];
    #pragma unroll
    for (int p = 0; p < PW; ++p) {
        const int tok0 = __builtin_amdgcn_readlane(tv, 8 + p);   // x[s0+p]
        a[p] = *(const f32x4*)(table + (size_t)tok0 * D_DIM + dcol);
    }

    // ---- phase 2: rare blank-accumulation corrections ----
    #pragma unroll
    for (int p = 0; p < PW; ++p) {
        const int s = s0 + p;
        // v[m] = blank(x[s-m]), m = 0..8, from ballot window
        const unsigned u  = (W >> p) & 0x1FFu;
        const unsigned v  = __builtin_bitreverse32(u) >> 23;     // reverse9
        const unsigned valid = (s >= 8) ? 0xffu : ((1u << s) - 1u);
        const unsigned mask  =
            __builtin_amdgcn_readfirstlane(v & ~(v >> 1) & valid);
        const unsigned long long pk = cTab.v[mask];              // packed c[1..8]
        if (pk) {                                                // ~6% of positions
            #pragma unroll
            for (int m = 1; m < 9; ++m) {
                const int cf = (int)((pk >> ((m - 1) * 8)) & 0xff);
                if (cf != 0) {
                    const float fc = (float)cf;
                    const int tkm = __builtin_amdgcn_readlane(tv, 8 + p - m);
                    a[p] += fc * *(const f32x4*)(table + (size_t)tkm * D_DIM + dcol);
                }
            }
        }
    }

    // ---- phase 3: batched nontemporal stores ----
    float* __restrict__ ob = out + (size_t)pos0 * D_DIM + dcol;
    #pragma unroll
    for (int p = 0; p < PW; ++p)
        __builtin_nontemporal_store(a[p], (f32x4*)(ob + p * D_DIM));
}

extern "C" void kernel_launch(void* const* d_in, const int* in_sizes, int n_in,
                              void* d_out, int out_size, void* d_ws, size_t ws_size,
                              hipStream_t stream) {
    const int*   x     = (const int*)d_in[0];
    const float* table = (const float*)d_in[1];
    float*       out   = (float*)d_out;

    const int BS = in_sizes[0];                      // B * S = 16384
    const int grid = (BS / PB) * NXCD;               // 4096 blocks
    blank_emb_kernel<<<grid, 256, 0, stream>>>(x, table, out);
}

// Round 7
// 26.923 us; speedup vs baseline: 1.6851x; 1.6851x over previous
//
#include <hip/hip_runtime.h>

// BlankEmbedding: out[b,s,:] = sum_{m=0..8} c[m] * emb_table[x[b,s-m], :]
// c[m] from 256-entry constexpr LUT over the 8 preblank bits (verified R2-R6).
// Structure = R5 (best known): XCD-pinned D-chunking (chunk = bid & 7 -> 2 MiB
// table slice per XCD L2), 2 positions per wave, nontemporal stores.
// Single change vs R5: the 18 per-wave token loads are replaced by ONE
// predicated 16-lane window load + ONE ballot; tokens via constant-index
// readlane, blank masks via SALU shifts (bit math verified in R6).

constexpr int S_LEN = 4096;
constexpr int D_DIM = 2048;
constexpr int NXCD  = 8;
constexpr int CW    = D_DIM / NXCD;   // 256 floats = 1 KiB per chunk
constexpr int PW    = 2;              // positions per wave
constexpr int PB    = 4 * PW;         // 8 positions per block (4 waves)

typedef float f32x4 __attribute__((ext_vector_type(4)));

struct CoefTab { unsigned long long v[256]; };

constexpr CoefTab make_tab() {
    CoefTab t{};
    for (int mask = 0; mask < 256; ++mask) {
        int p[9] = {};
        for (int i = 1; i <= 8; ++i) p[i] = (mask >> (i - 1)) & 1;
        int C[9][9] = {};
        for (int j = 0; j < 9; ++j) C[j][0] = 1;
        for (int k = 1; k <= 8; ++k)
            for (int j = 0; j + k <= 8; ++j)
                for (int m = 8; m >= 1; --m)
                    C[j][m] += p[j + k] * C[j + 1][m - 1];
        unsigned long long pack = 0ULL;
        for (int m = 1; m <= 8; ++m)
            pack |= (unsigned long long)(C[0][m] & 0xff) << ((m - 1) * 8);
        t.v[mask] = pack;
    }
    return t;
}

__device__ __constant__ CoefTab cTab = make_tab();

__global__ __launch_bounds__(256)
void blank_emb_kernel(const int* __restrict__ x,
                      const float* __restrict__ table,
                      float* __restrict__ out) {
    const int bid  = blockIdx.x;
    const int c    = bid & (NXCD - 1);      // D-chunk; round-robin -> XCD-pinned
    const int g    = bid >> 3;              // position group of PB positions
    const int wave = (int)threadIdx.x >> 6;
    const int lane = (int)threadIdx.x & 63;
    const int dcol = c * CW + lane * 4;

    const int pos0 = g * PB + wave * PW;    // wave's first flattened b*S + s
    const int s0   = pos0 & (S_LEN - 1);
    const int* __restrict__ xb = x + (pos0 - s0);

    // ---- one 16-lane token window: t = s0 - 8 + lane, lanes 0..15 ----
    int tv = 2048;                          // sentinel: non-blank
    const int t = s0 - 8 + lane;
    if (lane < 16 && t >= 0 && t < S_LEN) tv = xb[t];
    const unsigned W = (unsigned)__ballot(tv < 16);   // blank bits, lane = t-s0+8

    #pragma unroll
    for (int p = 0; p < PW; ++p) {
        const int s = s0 + p;

        const int tok0 = __builtin_amdgcn_readlane(tv, 8 + p);   // x[s]
        f32x4 a = *(const f32x4*)(table + (size_t)tok0 * D_DIM + dcol);

        // v bit m = blank(x[s-m]), m = 0..8
        const unsigned u  = (W >> p) & 0x1FFu;
        const unsigned v  = __builtin_bitreverse32(u) >> 23;     // reverse9
        const unsigned valid = (s >= 8) ? 0xffu : ((1u << s) - 1u);
        const unsigned mask  =
            __builtin_amdgcn_readfirstlane(v & ~(v >> 1) & valid);
        const unsigned long long pk = cTab.v[mask];              // packed c[1..8]

        if (pk) {                                                // ~6% of positions
            #pragma unroll
            for (int m = 1; m < 9; ++m) {
                const int cf = (int)((pk >> ((m - 1) * 8)) & 0xff);
                if (cf != 0) {
                    const float fc = (float)cf;
                    const int tkm = __builtin_amdgcn_readlane(tv, 8 + p - m);
                    a += fc * *(const f32x4*)(table + (size_t)tkm * D_DIM + dcol);
                }
            }
        }

        __builtin_nontemporal_store(
            a, (f32x4*)(out + (size_t)(pos0 + p) * D_DIM + dcol));
    }
}

extern "C" void kernel_launch(void* const* d_in, const int* in_sizes, int n_in,
                              void* d_out, int out_size, void* d_ws, size_t ws_size,
                              hipStream_t stream) {
    const int*   x     = (const int*)d_in[0];
    const float* table = (const float*)d_in[1];
    float*       out   = (float*)d_out;

    const int BS = in_sizes[0];                      // B * S = 16384
    const int grid = (BS / PB) * NXCD;               // 16384 blocks
    blank_emb_kernel<<<grid, 256, 0, stream>>>(x, table, out);
}